// Round 16
// baseline (231.858 us; speedup 1.0000x reference)
//
#include <hip/hip_runtime.h>

#define N_NODES 50000
#define N_EDGES 800000
#define FEA 128
#define NL 3
#define AH 512
#define NG 64
#define NBLK 196   // ceil(50000/256)

typedef short bf16x8 __attribute__((ext_vector_type(8)));
typedef float f32x4 __attribute__((ext_vector_type(4)));
typedef uint  u32x4 __attribute__((ext_vector_type(4)));

__device__ __forceinline__ ushort f2bf(float f) {   // RTN-even
    uint u = __float_as_uint(f);
    uint r = u + 0x7FFFu + ((u >> 16) & 1u);
    return (ushort)(r >> 16);
}
__device__ __forceinline__ float bf2f(ushort u) {
    return __uint_as_float((uint)u << 16);
}

// Column-sliced layouts: 4 slices of 64B (32 bf16 features) per row.
#define HS ((size_t)(N_NODES + 1) * 32)   // ushorts per H slice
#define XS ((size_t)N_NODES * 32)         // ushorts per X slice

// ---------------- fused: degree+rank | x->Xcs | convW split-T | H pad rows ----------------
#define DA 3125            // deg blocks (3125*256 = 800000 edges)
#define DB (DA + 3125)     // x conversion: 800000 8-feature chunks
#define DC (DB + 192)      // conv W split-transpose (3*16384)
#define DD (DC + 1)        // pad row zero
__global__ __launch_bounds__(256) void k_deg_prep(const int* __restrict__ dst,
                                                  int* __restrict__ deg,
                                                  ushort* __restrict__ rank,
                                                  const float* __restrict__ x,
                                                  ushort* __restrict__ X,
                                                  const float* __restrict__ convW,
                                                  ushort* __restrict__ WhiT,
                                                  ushort* __restrict__ WloT,
                                                  ushort* __restrict__ H) {
    int blk = blockIdx.x;
    if (blk < DA) {                        // degree histogram + rank
        int i = blk * 256 + threadIdx.x;
        rank[i] = (ushort)atomicAdd(&deg[dst[i]], 1);
    } else if (blk < DB) {                 // x -> column-sliced X bf16 (8 floats/thread)
        int i = (blk - DA) * 256 + threadIdx.x;   // chunk id, 0..799999
        int node = i >> 4, c8 = i & 15;           // features c8*8 .. c8*8+7
        const float* xr = x + (size_t)node * FEA + c8 * 8;
        float4 u0 = *(const float4*)xr;
        float4 u1 = *(const float4*)(xr + 4);
        float xs[8] = {u0.x, u0.y, u0.z, u0.w, u1.x, u1.y, u1.z, u1.w};
        ushort hs[8];
#pragma unroll
        for (int k = 0; k < 8; ++k) hs[k] = f2bf(xs[k]);
        u32x4 hv;
        hv.x = (uint)hs[0] | ((uint)hs[1] << 16);
        hv.y = (uint)hs[2] | ((uint)hs[3] << 16);
        hv.z = (uint)hs[4] | ((uint)hs[5] << 16);
        hv.w = (uint)hs[6] | ((uint)hs[7] << 16);
        *(u32x4*)(X + (size_t)(c8 >> 2) * XS + (size_t)node * 32 + (c8 & 3) * 8) = hv;
    } else if (blk < DC) {                 // conv W split-transpose
        int t = (blk - DB) * 256 + threadIdx.x;     // 0..49151
        int l = t >> 14, r = t & 16383;
        int k = r >> 7, c = r & 127;
        float w = convW[t];
        ushort h = f2bf(w);
        WhiT[(size_t)l * 16384 + c * FEA + k] = h;
        WloT[(size_t)l * 16384 + c * FEA + k] = f2bf(w - bf2f(h));
    } else {                               // zero H pad rows (4 slices x 64B)
        if (threadIdx.x < 64) {
            int c = threadIdx.x >> 4, j = threadIdx.x & 15;
            ((uint*)H)[(size_t)c * (HS / 2) + (size_t)N_NODES * 16 + j] = 0;
        }
    }
}

// ---------------- scan helpers ----------------
__device__ __forceinline__ int block_scan_incl(int v, int* wsum) {
    int lane = threadIdx.x & 63, w = threadIdx.x >> 6;
    int s = v;
#pragma unroll
    for (int off = 1; off < 64; off <<= 1) {
        int t = __shfl_up(s, off);
        if (lane >= off) s += t;
    }
    if (lane == 63) wsum[w] = s;
    __syncthreads();
    int woff = 0;
    for (int k = 0; k < w; ++k) woff += wsum[k];
    return woff + s;  // block-wide inclusive
}

// scan1: rowptr local scan + dinv + per-block degree-bin histogram
__global__ __launch_bounds__(256) void k_scan1(const int* __restrict__ deg,
                                               int* __restrict__ rowptr,
                                               int* __restrict__ bsum,
                                               float* __restrict__ dinv,
                                               int* __restrict__ bhist) {
    __shared__ int wsum[4];
    __shared__ int bh[16];
    if (threadIdx.x < 16) bh[threadIdx.x] = 0;
    int i = blockIdx.x * 256 + threadIdx.x;
    int v = (i < N_NODES) ? deg[i] : 0;
    int pv = (v + 7) & ~7;                       // pad to multiple of 8
    int incl = block_scan_incl(pv, wsum);        // contains a __syncthreads
    if (i < N_NODES) {
        rowptr[i] = incl - pv;                   // local exclusive
        dinv[i] = rsqrtf((float)v + 1.0f);
        int bin = min(pv >> 3, 15);
        atomicAdd(&bh[bin], 1);
    }
    if (threadIdx.x == 255) bsum[blockIdx.x] = incl;
    __syncthreads();
    if (threadIdx.x < 16) bhist[threadIdx.x * NBLK + blockIdx.x] = bh[threadIdx.x];
}

// scan2: block-sum scan (rowptr) + flattened bin-major scan (perm offsets)
#define BH_N (16 * NBLK)   // 3136
__global__ __launch_bounds__(256) void k_scan2(int* __restrict__ bsum,
                                               int* __restrict__ boff,
                                               int* __restrict__ rowptr,
                                               const int* __restrict__ bhist,
                                               int* __restrict__ boffs) {
    __shared__ int wsum[4];
    int v = (threadIdx.x < NBLK) ? bsum[threadIdx.x] : 0;
    int incl = block_scan_incl(v, wsum);
    if (threadIdx.x < NBLK) boff[threadIdx.x] = incl - v;
    if (threadIdx.x == NBLK - 1) rowptr[N_NODES] = incl;  // total padded edges
    __syncthreads();
    // phase B: exclusive scan of bhist[0..3135] (bin-major)
    __shared__ int wsum2[4];
    int base = threadIdx.x * 13;   // 256*13 = 3328 >= 3136
    int vals[13];
    int mysum = 0;
#pragma unroll
    for (int k = 0; k < 13; ++k) {
        int idx = base + k;
        int t = (idx < BH_N) ? bhist[idx] : 0;
        vals[k] = mysum;
        mysum += t;
    }
    int incl2 = block_scan_incl(mysum, wsum2);
    int excl = incl2 - mysum;
#pragma unroll
    for (int k = 0; k < 13; ++k) {
        int idx = base + k;
        if (idx < BH_N) boffs[idx] = excl + vals[k];
    }
}

// scan3: finalize rowptr + scatter degree-sorted permutation
__global__ __launch_bounds__(256) void k_scan3(int* __restrict__ rowptr,
                                               const int* __restrict__ boff,
                                               const int* __restrict__ deg,
                                               const int* __restrict__ boffs,
                                               int* __restrict__ perm) {
    __shared__ int cur[16];
    if (threadIdx.x < 16) cur[threadIdx.x] = boffs[threadIdx.x * NBLK + blockIdx.x];
    __syncthreads();
    int i = blockIdx.x * 256 + threadIdx.x;
    if (i < N_NODES) {
        rowptr[i] += boff[blockIdx.x];
        int pv = (deg[i] + 7) & ~7;
        int bin = min(pv >> 3, 15);
        int slot = atomicAdd(&cur[bin], 1);
        perm[slot] = i;
    }
}

// ---------------- fused: CSR fill | pad slots | graph bounds ----------------
#define FA 3125
#define FB (FA + NBLK)
#define FC (FB + NBLK)
__global__ __launch_bounds__(256) void k_fill2(const int* __restrict__ src,
                                               const int* __restrict__ dst,
                                               const int* __restrict__ rowptr,
                                               const ushort* __restrict__ rank,
                                               const int* __restrict__ deg,
                                               const int* __restrict__ batch,
                                               ushort* __restrict__ eidx,
                                               int* __restrict__ gstart) {
    int blk = blockIdx.x;
    if (blk < FA) {                        // CSR fill (no atomics)
        int e = blk * 256 + threadIdx.x;
        eidx[rowptr[dst[e]] + (int)rank[e]] = (ushort)src[e];
    } else if (blk < FB) {                 // pad slots -> zero row
        int i = (blk - FA) * 256 + threadIdx.x;
        if (i < N_NODES) {
            int d = deg[i], r = rowptr[i];
            int pd = (d + 7) & ~7;
            for (int k = d; k < pd; ++k) eidx[r + k] = (ushort)N_NODES;
        }
    } else {                               // graph bounds from sorted batch
        int i = (blk - FB) * 256 + threadIdx.x;
        if (i < N_NODES) {
            int b = batch[i];
            int bp = (i == 0) ? -1 : batch[i - 1];
            for (int g = bp + 1; g <= b; ++g) gstart[g] = i;
            if (i == N_NODES - 1)
                for (int g = b + 1; g <= NG; ++g) gstart[g] = N_NODES;
        }
    }
}

// ---------------- MFMA GEMM: H'cs(bf16) = dinv * (Xcs @ (Whi+Wlo)) ----------------
__global__ __launch_bounds__(256) void k_gemm(const ushort* __restrict__ X,
                                              const ushort* __restrict__ WhiT,
                                              const ushort* __restrict__ WloT,
                                              const float* __restrict__ dinv,
                                              ushort* __restrict__ H) {
    const int wv = threadIdx.x >> 6;
    const int lane = threadIdx.x & 63;
    const int lr = lane & 15;
    const int lk = lane >> 4;

    bf16x8 bhi[2][4], blo[2][4];
#pragma unroll
    for (int ct = 0; ct < 2; ++ct) {
        int col = wv * 32 + ct * 16 + lr;
#pragma unroll
        for (int kf = 0; kf < 4; ++kf) {
            bhi[ct][kf] = *(const bf16x8*)(WhiT + (size_t)col * FEA + kf * 32 + lk * 8);
            blo[ct][kf] = *(const bf16x8*)(WloT + (size_t)col * FEA + kf * 32 + lk * 8);
        }
    }

    for (int rt = blockIdx.x; rt < N_NODES / 16; rt += gridDim.x) {
        int r0 = rt * 16;
        bf16x8 a[4];
#pragma unroll
        for (int kf = 0; kf < 4; ++kf) {
            a[kf] = *(const bf16x8*)(X + (size_t)kf * XS + (size_t)(r0 + lr) * 32 + lk * 8);
        }
        f32x4 acc0 = {0.f, 0.f, 0.f, 0.f};
        f32x4 acc1 = {0.f, 0.f, 0.f, 0.f};
#pragma unroll
        for (int kf = 0; kf < 4; ++kf) {
            acc0 = __builtin_amdgcn_mfma_f32_16x16x32_bf16(a[kf], bhi[0][kf], acc0, 0, 0, 0);
            acc0 = __builtin_amdgcn_mfma_f32_16x16x32_bf16(a[kf], blo[0][kf], acc0, 0, 0, 0);
            acc1 = __builtin_amdgcn_mfma_f32_16x16x32_bf16(a[kf], bhi[1][kf], acc1, 0, 0, 0);
            acc1 = __builtin_amdgcn_mfma_f32_16x16x32_bf16(a[kf], blo[1][kf], acc1, 0, 0, 0);
        }
#pragma unroll
        for (int reg = 0; reg < 4; ++reg) {
            int orow = r0 + lk * 4 + reg;
            float s = dinv[orow];
            H[(size_t)wv * HS + (size_t)orow * 32 + lr]      = f2bf(acc0[reg] * s);
            H[(size_t)wv * HS + (size_t)orow * 32 + 16 + lr] = f2bf(acc1[reg] * s);
        }
    }
}

// ---------------- gather: 4 lanes/node x one 64B slice; degree-sorted perm ----------------
#define GNPB 64    // nodes per block
#define GNB ((N_NODES + GNPB - 1) / GNPB)
__global__ __launch_bounds__(256) void k_gather(const int* __restrict__ rowptr,
                                                const ushort* __restrict__ eidx,
                                                const float* __restrict__ dinv,
                                                const ushort* __restrict__ H,
                                                const float* __restrict__ b,
                                                const int* __restrict__ perm,
                                                ushort* __restrict__ X) {
    int c = blockIdx.x & 3;
    int pi = (blockIdx.x >> 2) * GNPB + (threadIdx.x >> 2);
    int l4 = threadIdx.x & 3;              // uint4 offset within 64B slice row
    if (pi >= N_NODES) return;
    int node = perm[pi];
    const uint4* Hs = (const uint4*)H + (size_t)c * (N_NODES + 1) * 4;
    int r0 = rowptr[node], r1 = rowptr[node + 1];

    float a[8] = {0.f, 0.f, 0.f, 0.f, 0.f, 0.f, 0.f, 0.f};
#define ACC8(u)                                                              \
    do {                                                                     \
        a[0] += __uint_as_float((u).x << 16);                                \
        a[1] += __uint_as_float((u).x & 0xffff0000u);                        \
        a[2] += __uint_as_float((u).y << 16);                                \
        a[3] += __uint_as_float((u).y & 0xffff0000u);                        \
        a[4] += __uint_as_float((u).z << 16);                                \
        a[5] += __uint_as_float((u).z & 0xffff0000u);                        \
        a[6] += __uint_as_float((u).w << 16);                                \
        a[7] += __uint_as_float((u).w & 0xffff0000u);                        \
    } while (0)

    uint4 sv = Hs[(size_t)node * 4 + l4];  // self term
    ACC8(sv);

    for (int j = r0; j < r1; j += 8) {     // j 8-aligned -> 16B-aligned
        uint4 ev = *(const uint4*)(eidx + j);   // same addr across node's 4 lanes
        int s0 = ev.x & 0xffff, s1 = ev.x >> 16;
        int s2 = ev.y & 0xffff, s3 = ev.y >> 16;
        int s4 = ev.z & 0xffff, s5 = ev.z >> 16;
        int s6 = ev.w & 0xffff, s7 = ev.w >> 16;
        uint4 h0 = Hs[(size_t)s0 * 4 + l4];
        uint4 h1 = Hs[(size_t)s1 * 4 + l4];
        uint4 h2 = Hs[(size_t)s2 * 4 + l4];
        uint4 h3 = Hs[(size_t)s3 * 4 + l4];
        uint4 h4 = Hs[(size_t)s4 * 4 + l4];
        uint4 h5 = Hs[(size_t)s5 * 4 + l4];
        uint4 h6 = Hs[(size_t)s6 * 4 + l4];
        uint4 h7 = Hs[(size_t)s7 * 4 + l4];
        ACC8(h0); ACC8(h1); ACC8(h2); ACC8(h3);
        ACC8(h4); ACC8(h5); ACC8(h6); ACC8(h7);
    }
#undef ACC8

    float di = dinv[node];
    const float4* b4 = (const float4*)(b + c * 32 + l4 * 8);
    float4 bb0 = b4[0], bb1 = b4[1];
    float o[8];
    o[0] = fmaxf(a[0] * di + bb0.x, 0.f);
    o[1] = fmaxf(a[1] * di + bb0.y, 0.f);
    o[2] = fmaxf(a[2] * di + bb0.z, 0.f);
    o[3] = fmaxf(a[3] * di + bb0.w, 0.f);
    o[4] = fmaxf(a[4] * di + bb1.x, 0.f);
    o[5] = fmaxf(a[5] * di + bb1.y, 0.f);
    o[6] = fmaxf(a[6] * di + bb1.z, 0.f);
    o[7] = fmaxf(a[7] * di + bb1.w, 0.f);

    ushort hs[8];
#pragma unroll
    for (int i = 0; i < 8; ++i) hs[i] = f2bf(o[i]);
    u32x4 hv;
    hv.x = (uint)hs[0] | ((uint)hs[1] << 16);
    hv.y = (uint)hs[2] | ((uint)hs[3] << 16);
    hv.z = (uint)hs[4] | ((uint)hs[5] << 16);
    hv.w = (uint)hs[6] | ((uint)hs[7] << 16);
    __builtin_nontemporal_store(hv, (u32x4*)(X + (size_t)c * XS + (size_t)node * 32 + l4 * 8));
}

// ---------------- pool + node head (no atomics), 16 partials/graph ----------------
__global__ __launch_bounds__(256) void k_pool(const ushort* __restrict__ X,
                                              const int* __restrict__ gstart,
                                              const float* __restrict__ nw,
                                              const float* __restrict__ nbp,
                                              float* __restrict__ out_node,
                                              float* __restrict__ psum_part) {
    int g = blockIdx.x >> 4, p = blockIdx.x & 15;
    int s = gstart[g], e = gstart[g + 1];
    int len = e - s;
    int lp = (len + 15) >> 4;
    int ps = s + p * lp, pe = min(ps + lp, e);
    int q = threadIdx.x >> 6, lane = threadIdx.x & 63;
    const uint* hb = (const uint*)X + (size_t)(lane >> 4) * (XS / 2) + (lane & 15);
    float2 w = ((const float2*)nw)[lane];
    float nbv = nbp[0];
    float2 acc = {0.f, 0.f};
    for (int node = ps + q; node < pe; node += 4) {
        uint hv = hb[(size_t)node * 16];
        float2 v;
        v.x = bf2f((ushort)hv);
        v.y = bf2f((ushort)(hv >> 16));
        acc.x += v.x; acc.y += v.y;
        float dot = v.x * w.x + v.y * w.y;
#pragma unroll
        for (int off = 32; off; off >>= 1) dot += __shfl_down(dot, off);
        if (lane == 0) out_node[node] = dot + nbv;
    }
    __shared__ float lds[4 * FEA];
    lds[q * FEA + lane * 2 + 0] = acc.x;
    lds[q * FEA + lane * 2 + 1] = acc.y;
    __syncthreads();
    if (threadIdx.x < FEA) {
        psum_part[(size_t)blockIdx.x * FEA + threadIdx.x] =
            lds[threadIdx.x] + lds[FEA + threadIdx.x] +
            lds[2 * FEA + threadIdx.x] + lds[3 * FEA + threadIdx.x];
    }
}

// ---------------- MLP layer 1 (direct strided w1 reads) ----------------
__global__ __launch_bounds__(256) void k_mlp1(const float* __restrict__ psum_part,
                                              const int* __restrict__ gstart,
                                              const float* __restrict__ w1,
                                              const float* __restrict__ b1,
                                              float* __restrict__ h1ws) {
    __shared__ float feas[NG * 132];   // pad 132 to spread banks
    for (int idx = threadIdx.x; idx < NG * FEA; idx += 256) {
        int g = idx >> 7, f = idx & 127;
        const float* pp = psum_part + (size_t)g * 16 * FEA + f;
        float sum = 0.f;
#pragma unroll
        for (int p = 0; p < 16; ++p) sum += pp[p * FEA];
        float cnt = fmaxf((float)(gstart[g + 1] - gstart[g]), 1.0f);
        feas[g * 132 + f] = sum / cnt;
    }
    __syncthreads();
    int g = threadIdx.x >> 2, jj = threadIdx.x & 3;
    int j = blockIdx.x * 4 + jj;
    const float* fr = feas + g * 132;
    float a0 = 0.f, a1 = 0.f, a2 = 0.f, a3 = 0.f;
#pragma unroll 8
    for (int k = 0; k < FEA; k += 4) {
        a0 += fr[k + 0] * w1[(k + 0) * AH + j];
        a1 += fr[k + 1] * w1[(k + 1) * AH + j];
        a2 += fr[k + 2] * w1[(k + 2) * AH + j];
        a3 += fr[k + 3] * w1[(k + 3) * AH + j];
    }
    h1ws[(size_t)g * AH + j] = fmaxf((a0 + a1) + (a2 + a3) + b1[j], 0.f);
}

// ---------------- MLP layer 2 (direct strided w2 reads) ----------------
__global__ __launch_bounds__(256) void k_mlp2(const float* __restrict__ h1ws,
                                              const float* __restrict__ w2,
                                              const float* __restrict__ b2,
                                              float* __restrict__ out_fea) {
    int f = blockIdx.x;
    int g = threadIdx.x >> 2, q = threadIdx.x & 3;
    const float* hr = h1ws + (size_t)g * AH + q * 128;
    const float* wr = w2 + (size_t)q * 128 * FEA + f;
    float a0 = 0.f, a1 = 0.f, a2 = 0.f, a3 = 0.f;
#pragma unroll 8
    for (int k = 0; k < 128; k += 4) {
        a0 += hr[k + 0] * wr[(k + 0) * FEA];
        a1 += hr[k + 1] * wr[(k + 1) * FEA];
        a2 += hr[k + 2] * wr[(k + 2) * FEA];
        a3 += hr[k + 3] * wr[(k + 3) * FEA];
    }
    float p = (a0 + a1) + (a2 + a3);
    p += __shfl_xor(p, 1);
    p += __shfl_xor(p, 2);
    if (q == 0) out_fea[(size_t)g * FEA + f] = p + b2[f];
}

extern "C" void kernel_launch(void* const* d_in, const int* in_sizes, int n_in,
                              void* d_out, int out_size, void* d_ws, size_t ws_size,
                              hipStream_t stream) {
    const float* x     = (const float*)d_in[0];
    const int*   ei    = (const int*)d_in[1];
    const int*   batch = (const int*)d_in[2];
    const float* convW = (const float*)d_in[3];
    const float* convb = (const float*)d_in[4];
    const float* w1    = (const float*)d_in[5];
    const float* b1    = (const float*)d_in[6];
    const float* w2    = (const float*)d_in[7];
    const float* b2    = (const float*)d_in[8];
    const float* nw    = (const float*)d_in[9];
    const float* nb    = (const float*)d_in[10];
    float* out = (float*)d_out;

    // workspace layout (4-byte word offsets)
    char* wsb = (char*)d_ws;
    int*    deg    = (int*)wsb;                        // 50000
    float*  dinv   = (float*)(wsb + 50048ll * 4);      // 50000
    int*    rowptr = (int*)(wsb + 100096ll * 4);       // 50001
    int*    bsum   = (int*)(wsb + 150144ll * 4);       // 196
    int*    boff   = (int*)(wsb + 150344ll * 4);       // 196
    int*    gstart = (int*)(wsb + 150544ll * 4);       // 65
    int*    bhist  = (int*)(wsb + 150640ll * 4);       // 3136
    int*    boffs  = (int*)(wsb + 153792ll * 4);       // 3136
    int*    perm   = (int*)(wsb + 156944ll * 4);       // 50048
    int*    rankw  = (int*)(wsb + 207008ll * 4);       // 400000 words
    ushort* rank   = (ushort*)rankw;                   // 800000 ushort
    float*  h1ws   = (float*)rankw;                    // 32768 w (after fill)
    ushort* eidx   = (ushort*)(wsb + 950656ll * 4);    // <=1.3M ushort
    ushort* H      = (ushort*)(wsb + 1600672ll * 4);   // 4*(N+1)*32 bf16
    ushort* X      = (ushort*)(wsb + 4800736ll * 4);   // 4*N*32 bf16
    float*  psum_part = (float*)(wsb + 11200736ll * 4);// 1024*128 floats
    // WhiT/WloT alias psum_part: dead after last gemm, psum written by k_pool later
    ushort* WhiT   = (ushort*)psum_part;               // 49152 shorts
    ushort* WloT   = WhiT + 49152;                     // 49152 shorts

    const int* srcp = ei;
    const int* dstp = ei + N_EDGES;

    // ---- CSR build + prep ----
    hipMemsetAsync(deg, 0, N_NODES * sizeof(int), stream);
    k_deg_prep<<<DD, 256, 0, stream>>>(dstp, deg, rank, x, X, convW, WhiT, WloT, H);
    k_scan1<<<NBLK, 256, 0, stream>>>(deg, rowptr, bsum, dinv, bhist);
    k_scan2<<<1, 256, 0, stream>>>(bsum, boff, rowptr, bhist, boffs);
    k_scan3<<<NBLK, 256, 0, stream>>>(rowptr, boff, deg, boffs, perm);
    k_fill2<<<FC, 256, 0, stream>>>(srcp, dstp, rowptr, rank, deg, batch, eidx, gstart);

    // ---- GCN layers ----
    for (int l = 0; l < NL; ++l) {
        k_gemm<<<1024, 256, 0, stream>>>(X, WhiT + (size_t)l * 16384,
                                         WloT + (size_t)l * 16384, dinv, H);
        k_gather<<<GNB * 4, 256, 0, stream>>>(
            rowptr, eidx, dinv, H, convb + (size_t)l * FEA, perm, X);
    }

    // ---- heads ----
    k_pool<<<NG * 16, 256, 0, stream>>>(X, gstart, nw, nb, out, psum_part);
    k_mlp1<<<128, 256, 0, stream>>>(psum_part, gstart, w1, b1, h1ws);
    k_mlp2<<<128, 256, 0, stream>>>(h1ws, w2, b2, out + N_NODES);
}

// Round 17
// 224.664 us; speedup vs baseline: 1.0320x; 1.0320x over previous
//
#include <hip/hip_runtime.h>

#define N_NODES 50000
#define N_EDGES 800000
#define FEA 128
#define NL 3
#define AH 512
#define NG 64
#define NBLK 196   // ceil(50000/256)

typedef short bf16x8 __attribute__((ext_vector_type(8)));
typedef float f32x4 __attribute__((ext_vector_type(4)));
typedef uint  u32x4 __attribute__((ext_vector_type(4)));

__device__ __forceinline__ ushort f2bf(float f) {   // RTN-even
    uint u = __float_as_uint(f);
    uint r = u + 0x7FFFu + ((u >> 16) & 1u);
    return (ushort)(r >> 16);
}
__device__ __forceinline__ float bf2f(ushort u) {
    return __uint_as_float((uint)u << 16);
}

// Column-sliced layouts: 4 slices of 64B (32 bf16 features) per row.
#define HS ((size_t)(N_NODES + 1) * 32)   // ushorts per H slice
#define XS ((size_t)N_NODES * 32)         // ushorts per X slice

// ---------------- fused: sharded degree+rank | x->Xcs | convW split-T | H pad rows ----------------
#define DA 3125            // deg blocks (3125*256 = 800000 edges)
#define DB (DA + 3125)     // x conversion: 800000 8-feature chunks
#define DC (DB + 192)      // conv W split-transpose (3*16384)
#define DD (DC + 1)        // pad row zero
__global__ __launch_bounds__(256) void k_deg_prep(const int* __restrict__ dst,
                                                  int* __restrict__ hist,
                                                  ushort* __restrict__ rank,
                                                  const float* __restrict__ x,
                                                  ushort* __restrict__ X,
                                                  const float* __restrict__ convW,
                                                  ushort* __restrict__ WhiT,
                                                  ushort* __restrict__ WloT,
                                                  ushort* __restrict__ H) {
    int blk = blockIdx.x;
    if (blk < DA) {                        // sharded histogram: copy = blk&7 (XCD-local)
        int i = blk * 256 + threadIdx.x;
        rank[i] = (ushort)atomicAdd(&hist[(blk & 7) * N_NODES + dst[i]], 1);
    } else if (blk < DB) {                 // x -> column-sliced X bf16 (8 floats/thread)
        int i = (blk - DA) * 256 + threadIdx.x;   // chunk id, 0..799999
        int node = i >> 4, c8 = i & 15;           // features c8*8 .. c8*8+7
        const float* xr = x + (size_t)node * FEA + c8 * 8;
        float4 u0 = *(const float4*)xr;
        float4 u1 = *(const float4*)(xr + 4);
        float xs[8] = {u0.x, u0.y, u0.z, u0.w, u1.x, u1.y, u1.z, u1.w};
        ushort hs[8];
#pragma unroll
        for (int k = 0; k < 8; ++k) hs[k] = f2bf(xs[k]);
        u32x4 hv;
        hv.x = (uint)hs[0] | ((uint)hs[1] << 16);
        hv.y = (uint)hs[2] | ((uint)hs[3] << 16);
        hv.z = (uint)hs[4] | ((uint)hs[5] << 16);
        hv.w = (uint)hs[6] | ((uint)hs[7] << 16);
        *(u32x4*)(X + (size_t)(c8 >> 2) * XS + (size_t)node * 32 + (c8 & 3) * 8) = hv;
    } else if (blk < DC) {                 // conv W split-transpose
        int t = (blk - DB) * 256 + threadIdx.x;     // 0..49151
        int l = t >> 14, r = t & 16383;
        int k = r >> 7, c = r & 127;
        float w = convW[t];
        ushort h = f2bf(w);
        WhiT[(size_t)l * 16384 + c * FEA + k] = h;
        WloT[(size_t)l * 16384 + c * FEA + k] = f2bf(w - bf2f(h));
    } else {                               // zero H pad rows (4 slices x 64B)
        if (threadIdx.x < 64) {
            int c = threadIdx.x >> 4, j = threadIdx.x & 15;
            ((uint*)H)[(size_t)c * (HS / 2) + (size_t)N_NODES * 16 + j] = 0;
        }
    }
}

// ---------------- scan helpers ----------------
__device__ __forceinline__ int block_scan_incl(int v, int* wsum) {
    int lane = threadIdx.x & 63, w = threadIdx.x >> 6;
    int s = v;
#pragma unroll
    for (int off = 1; off < 64; off <<= 1) {
        int t = __shfl_up(s, off);
        if (lane >= off) s += t;
    }
    if (lane == 63) wsum[w] = s;
    __syncthreads();
    int woff = 0;
    for (int k = 0; k < w; ++k) woff += wsum[k];
    return woff + s;  // block-wide inclusive
}

// scan1: reduce hist copies -> deg, per-copy offsets, dinv, local rowptr scan
__global__ __launch_bounds__(256) void k_scan1(const int* __restrict__ hist,
                                               int* __restrict__ off,
                                               int* __restrict__ deg,
                                               int* __restrict__ rowptr,
                                               int* __restrict__ bsum,
                                               float* __restrict__ dinv) {
    __shared__ int wsum[4];
    int i = blockIdx.x * 256 + threadIdx.x;
    int tot = 0;
    if (i < N_NODES) {
#pragma unroll
        for (int y = 0; y < 8; ++y) {
            int t = hist[y * N_NODES + i];
            off[y * N_NODES + i] = tot;
            tot += t;
        }
    }
    int pv = (tot + 7) & ~7;                     // pad to multiple of 8
    int incl = block_scan_incl(pv, wsum);
    if (i < N_NODES) {
        rowptr[i] = incl - pv;                   // local exclusive
        deg[i] = tot;
        dinv[i] = rsqrtf((float)tot + 1.0f);
    }
    if (threadIdx.x == 255) bsum[blockIdx.x] = incl;
}

__global__ __launch_bounds__(256) void k_scan2(int* __restrict__ bsum,
                                               int* __restrict__ boff,
                                               int* __restrict__ rowptr) {
    __shared__ int wsum[4];
    int v = (threadIdx.x < NBLK) ? bsum[threadIdx.x] : 0;
    int incl = block_scan_incl(v, wsum);
    if (threadIdx.x < NBLK) boff[threadIdx.x] = incl - v;
    if (threadIdx.x == NBLK - 1) rowptr[N_NODES] = incl;  // total padded edges
}

__global__ __launch_bounds__(256) void k_scan3(int* __restrict__ rowptr,
                                               const int* __restrict__ boff) {
    int i = blockIdx.x * 256 + threadIdx.x;
    if (i < N_NODES) rowptr[i] += boff[blockIdx.x];
}

// ---------------- fused: CSR fill (sharded rank) | pad slots | graph bounds ----------------
#define FA 3125
#define FB (FA + NBLK)
#define FC (FB + NBLK)
__global__ __launch_bounds__(256) void k_fill2(const int* __restrict__ src,
                                               const int* __restrict__ dst,
                                               const int* __restrict__ rowptr,
                                               const ushort* __restrict__ rank,
                                               const int* __restrict__ off,
                                               const int* __restrict__ deg,
                                               const int* __restrict__ batch,
                                               ushort* __restrict__ eidx,
                                               int* __restrict__ gstart) {
    int blk = blockIdx.x;
    if (blk < FA) {                        // CSR fill (no atomics)
        int e = blk * 256 + threadIdx.x;
        int d = dst[e];
        int rg = off[(blk & 7) * N_NODES + d] + (int)rank[e];
        eidx[rowptr[d] + rg] = (ushort)src[e];
    } else if (blk < FB) {                 // pad slots -> zero row
        int i = (blk - FA) * 256 + threadIdx.x;
        if (i < N_NODES) {
            int d = deg[i], r = rowptr[i];
            int pd = (d + 7) & ~7;
            for (int k = d; k < pd; ++k) eidx[r + k] = (ushort)N_NODES;
        }
    } else {                               // graph bounds from sorted batch
        int i = (blk - FB) * 256 + threadIdx.x;
        if (i < N_NODES) {
            int b = batch[i];
            int bp = (i == 0) ? -1 : batch[i - 1];
            for (int g = bp + 1; g <= b; ++g) gstart[g] = i;
            if (i == N_NODES - 1)
                for (int g = b + 1; g <= NG; ++g) gstart[g] = N_NODES;
        }
    }
}

// ---------------- MFMA GEMM: H'cs(bf16) = dinv * (Xcs @ (Whi+Wlo)) ----------------
__global__ __launch_bounds__(256) void k_gemm(const ushort* __restrict__ X,
                                              const ushort* __restrict__ WhiT,
                                              const ushort* __restrict__ WloT,
                                              const float* __restrict__ dinv,
                                              ushort* __restrict__ H) {
    const int wv = threadIdx.x >> 6;
    const int lane = threadIdx.x & 63;
    const int lr = lane & 15;
    const int lk = lane >> 4;

    bf16x8 bhi[2][4], blo[2][4];
#pragma unroll
    for (int ct = 0; ct < 2; ++ct) {
        int col = wv * 32 + ct * 16 + lr;
#pragma unroll
        for (int kf = 0; kf < 4; ++kf) {
            bhi[ct][kf] = *(const bf16x8*)(WhiT + (size_t)col * FEA + kf * 32 + lk * 8);
            blo[ct][kf] = *(const bf16x8*)(WloT + (size_t)col * FEA + kf * 32 + lk * 8);
        }
    }

    for (int rt = blockIdx.x; rt < N_NODES / 16; rt += gridDim.x) {
        int r0 = rt * 16;
        bf16x8 a[4];
#pragma unroll
        for (int kf = 0; kf < 4; ++kf) {
            a[kf] = *(const bf16x8*)(X + (size_t)kf * XS + (size_t)(r0 + lr) * 32 + lk * 8);
        }
        f32x4 acc0 = {0.f, 0.f, 0.f, 0.f};
        f32x4 acc1 = {0.f, 0.f, 0.f, 0.f};
#pragma unroll
        for (int kf = 0; kf < 4; ++kf) {
            acc0 = __builtin_amdgcn_mfma_f32_16x16x32_bf16(a[kf], bhi[0][kf], acc0, 0, 0, 0);
            acc0 = __builtin_amdgcn_mfma_f32_16x16x32_bf16(a[kf], blo[0][kf], acc0, 0, 0, 0);
            acc1 = __builtin_amdgcn_mfma_f32_16x16x32_bf16(a[kf], bhi[1][kf], acc1, 0, 0, 0);
            acc1 = __builtin_amdgcn_mfma_f32_16x16x32_bf16(a[kf], blo[1][kf], acc1, 0, 0, 0);
        }
#pragma unroll
        for (int reg = 0; reg < 4; ++reg) {
            int orow = r0 + lk * 4 + reg;
            float s = dinv[orow];
            H[(size_t)wv * HS + (size_t)orow * 32 + lr]      = f2bf(acc0[reg] * s);
            H[(size_t)wv * HS + (size_t)orow * 32 + 16 + lr] = f2bf(acc1[reg] * s);
        }
    }
}

// ---------------- gather: 4 lanes/node x one 64B slice; c = blk&3 -> XCD-local ----------------
#define GNPB 64    // nodes per block
#define GNB ((N_NODES + GNPB - 1) / GNPB)
__global__ __launch_bounds__(256) void k_gather(const int* __restrict__ rowptr,
                                                const ushort* __restrict__ eidx,
                                                const float* __restrict__ dinv,
                                                const ushort* __restrict__ H,
                                                const float* __restrict__ b,
                                                ushort* __restrict__ X) {
    int c = blockIdx.x & 3;
    int node = (blockIdx.x >> 2) * GNPB + (threadIdx.x >> 2);
    int l4 = threadIdx.x & 3;              // uint4 offset within 64B slice row
    if (node >= N_NODES) return;
    const uint4* Hs = (const uint4*)H + (size_t)c * (N_NODES + 1) * 4;
    int r0 = rowptr[node], r1 = rowptr[node + 1];

    float a[8] = {0.f, 0.f, 0.f, 0.f, 0.f, 0.f, 0.f, 0.f};
#define ACC8(u)                                                              \
    do {                                                                     \
        a[0] += __uint_as_float((u).x << 16);                                \
        a[1] += __uint_as_float((u).x & 0xffff0000u);                        \
        a[2] += __uint_as_float((u).y << 16);                                \
        a[3] += __uint_as_float((u).y & 0xffff0000u);                        \
        a[4] += __uint_as_float((u).z << 16);                                \
        a[5] += __uint_as_float((u).z & 0xffff0000u);                        \
        a[6] += __uint_as_float((u).w << 16);                                \
        a[7] += __uint_as_float((u).w & 0xffff0000u);                        \
    } while (0)

    uint4 sv = Hs[(size_t)node * 4 + l4];  // self term
    ACC8(sv);

    for (int j = r0; j < r1; j += 8) {     // j 8-aligned -> 16B-aligned
        uint4 ev = *(const uint4*)(eidx + j);   // same addr across node's 4 lanes
        int s0 = ev.x & 0xffff, s1 = ev.x >> 16;
        int s2 = ev.y & 0xffff, s3 = ev.y >> 16;
        int s4 = ev.z & 0xffff, s5 = ev.z >> 16;
        int s6 = ev.w & 0xffff, s7 = ev.w >> 16;
        uint4 h0 = Hs[(size_t)s0 * 4 + l4];
        uint4 h1 = Hs[(size_t)s1 * 4 + l4];
        uint4 h2 = Hs[(size_t)s2 * 4 + l4];
        uint4 h3 = Hs[(size_t)s3 * 4 + l4];
        uint4 h4 = Hs[(size_t)s4 * 4 + l4];
        uint4 h5 = Hs[(size_t)s5 * 4 + l4];
        uint4 h6 = Hs[(size_t)s6 * 4 + l4];
        uint4 h7 = Hs[(size_t)s7 * 4 + l4];
        ACC8(h0); ACC8(h1); ACC8(h2); ACC8(h3);
        ACC8(h4); ACC8(h5); ACC8(h6); ACC8(h7);
    }
#undef ACC8

    float di = dinv[node];
    const float4* b4 = (const float4*)(b + c * 32 + l4 * 8);
    float4 bb0 = b4[0], bb1 = b4[1];
    float o[8];
    o[0] = fmaxf(a[0] * di + bb0.x, 0.f);
    o[1] = fmaxf(a[1] * di + bb0.y, 0.f);
    o[2] = fmaxf(a[2] * di + bb0.z, 0.f);
    o[3] = fmaxf(a[3] * di + bb0.w, 0.f);
    o[4] = fmaxf(a[4] * di + bb1.x, 0.f);
    o[5] = fmaxf(a[5] * di + bb1.y, 0.f);
    o[6] = fmaxf(a[6] * di + bb1.z, 0.f);
    o[7] = fmaxf(a[7] * di + bb1.w, 0.f);

    ushort hs[8];
#pragma unroll
    for (int i = 0; i < 8; ++i) hs[i] = f2bf(o[i]);
    u32x4 hv;
    hv.x = (uint)hs[0] | ((uint)hs[1] << 16);
    hv.y = (uint)hs[2] | ((uint)hs[3] << 16);
    hv.z = (uint)hs[4] | ((uint)hs[5] << 16);
    hv.w = (uint)hs[6] | ((uint)hs[7] << 16);
    __builtin_nontemporal_store(hv, (u32x4*)(X + (size_t)c * XS + (size_t)node * 32 + l4 * 8));
}

// ---------------- pool + node head (no atomics), 16 partials/graph ----------------
__global__ __launch_bounds__(256) void k_pool(const ushort* __restrict__ X,
                                              const int* __restrict__ gstart,
                                              const float* __restrict__ nw,
                                              const float* __restrict__ nbp,
                                              float* __restrict__ out_node,
                                              float* __restrict__ psum_part) {
    int g = blockIdx.x >> 4, p = blockIdx.x & 15;
    int s = gstart[g], e = gstart[g + 1];
    int len = e - s;
    int lp = (len + 15) >> 4;
    int ps = s + p * lp, pe = min(ps + lp, e);
    int q = threadIdx.x >> 6, lane = threadIdx.x & 63;
    const uint* hb = (const uint*)X + (size_t)(lane >> 4) * (XS / 2) + (lane & 15);
    float2 w = ((const float2*)nw)[lane];
    float nbv = nbp[0];
    float2 acc = {0.f, 0.f};
    for (int node = ps + q; node < pe; node += 4) {
        uint hv = hb[(size_t)node * 16];
        float2 v;
        v.x = bf2f((ushort)hv);
        v.y = bf2f((ushort)(hv >> 16));
        acc.x += v.x; acc.y += v.y;
        float dot = v.x * w.x + v.y * w.y;
#pragma unroll
        for (int off = 32; off; off >>= 1) dot += __shfl_down(dot, off);
        if (lane == 0) out_node[node] = dot + nbv;
    }
    __shared__ float lds[4 * FEA];
    lds[q * FEA + lane * 2 + 0] = acc.x;
    lds[q * FEA + lane * 2 + 1] = acc.y;
    __syncthreads();
    if (threadIdx.x < FEA) {
        psum_part[(size_t)blockIdx.x * FEA + threadIdx.x] =
            lds[threadIdx.x] + lds[FEA + threadIdx.x] +
            lds[2 * FEA + threadIdx.x] + lds[3 * FEA + threadIdx.x];
    }
}

// ---------------- MLP layer 1 (direct strided w1 reads) ----------------
__global__ __launch_bounds__(256) void k_mlp1(const float* __restrict__ psum_part,
                                              const int* __restrict__ gstart,
                                              const float* __restrict__ w1,
                                              const float* __restrict__ b1,
                                              float* __restrict__ h1ws) {
    __shared__ float feas[NG * 132];   // pad 132 to spread banks
    for (int idx = threadIdx.x; idx < NG * FEA; idx += 256) {
        int g = idx >> 7, f = idx & 127;
        const float* pp = psum_part + (size_t)g * 16 * FEA + f;
        float sum = 0.f;
#pragma unroll
        for (int p = 0; p < 16; ++p) sum += pp[p * FEA];
        float cnt = fmaxf((float)(gstart[g + 1] - gstart[g]), 1.0f);
        feas[g * 132 + f] = sum / cnt;
    }
    __syncthreads();
    int g = threadIdx.x >> 2, jj = threadIdx.x & 3;
    int j = blockIdx.x * 4 + jj;
    const float* fr = feas + g * 132;
    float a0 = 0.f, a1 = 0.f, a2 = 0.f, a3 = 0.f;
#pragma unroll 8
    for (int k = 0; k < FEA; k += 4) {
        a0 += fr[k + 0] * w1[(k + 0) * AH + j];
        a1 += fr[k + 1] * w1[(k + 1) * AH + j];
        a2 += fr[k + 2] * w1[(k + 2) * AH + j];
        a3 += fr[k + 3] * w1[(k + 3) * AH + j];
    }
    h1ws[(size_t)g * AH + j] = fmaxf((a0 + a1) + (a2 + a3) + b1[j], 0.f);
}

// ---------------- MLP layer 2 (direct strided w2 reads) ----------------
__global__ __launch_bounds__(256) void k_mlp2(const float* __restrict__ h1ws,
                                              const float* __restrict__ w2,
                                              const float* __restrict__ b2,
                                              float* __restrict__ out_fea) {
    int f = blockIdx.x;
    int g = threadIdx.x >> 2, q = threadIdx.x & 3;
    const float* hr = h1ws + (size_t)g * AH + q * 128;
    const float* wr = w2 + (size_t)q * 128 * FEA + f;
    float a0 = 0.f, a1 = 0.f, a2 = 0.f, a3 = 0.f;
#pragma unroll 8
    for (int k = 0; k < 128; k += 4) {
        a0 += hr[k + 0] * wr[(k + 0) * FEA];
        a1 += hr[k + 1] * wr[(k + 1) * FEA];
        a2 += hr[k + 2] * wr[(k + 2) * FEA];
        a3 += hr[k + 3] * wr[(k + 3) * FEA];
    }
    float p = (a0 + a1) + (a2 + a3);
    p += __shfl_xor(p, 1);
    p += __shfl_xor(p, 2);
    if (q == 0) out_fea[(size_t)g * FEA + f] = p + b2[f];
}

extern "C" void kernel_launch(void* const* d_in, const int* in_sizes, int n_in,
                              void* d_out, int out_size, void* d_ws, size_t ws_size,
                              hipStream_t stream) {
    const float* x     = (const float*)d_in[0];
    const int*   ei    = (const int*)d_in[1];
    const int*   batch = (const int*)d_in[2];
    const float* convW = (const float*)d_in[3];
    const float* convb = (const float*)d_in[4];
    const float* w1    = (const float*)d_in[5];
    const float* b1    = (const float*)d_in[6];
    const float* w2    = (const float*)d_in[7];
    const float* b2    = (const float*)d_in[8];
    const float* nw    = (const float*)d_in[9];
    const float* nb    = (const float*)d_in[10];
    float* out = (float*)d_out;

    // workspace layout (4-byte word offsets)
    char* wsb = (char*)d_ws;
    int*    deg    = (int*)wsb;                        // 50000
    float*  dinv   = (float*)(wsb + 50048ll * 4);      // 50000
    int*    rowptr = (int*)(wsb + 100096ll * 4);       // 50001
    int*    bsum   = (int*)(wsb + 150144ll * 4);       // 196
    int*    boff   = (int*)(wsb + 150344ll * 4);       // 196
    int*    gstart = (int*)(wsb + 150544ll * 4);       // 65
    int*    hist   = (int*)(wsb + 150656ll * 4);       // 8*50000
    int*    off    = (int*)(wsb + 550656ll * 4);       // 8*50000
    int*    rankw  = (int*)(wsb + 950656ll * 4);       // 400000 words
    ushort* rank   = (ushort*)rankw;                   // 800000 ushort
    float*  h1ws   = (float*)rankw;                    // 32768 w (after fill)
    ushort* eidx   = (ushort*)(wsb + 1350656ll * 4);   // <=1.3M ushort (650016 w)
    ushort* H      = (ushort*)(wsb + 2000672ll * 4);   // 4*(N+1)*32 bf16
    ushort* X      = (ushort*)(wsb + 5200736ll * 4);   // 4*N*32 bf16
    float*  psum_part = (float*)(wsb + 8400736ll * 4); // 1024*128 floats
    // WhiT/WloT alias psum_part: dead after last gemm, psum written by k_pool later
    ushort* WhiT   = (ushort*)psum_part;               // 49152 shorts
    ushort* WloT   = WhiT + 49152;                     // 49152 shorts

    const int* srcp = ei;
    const int* dstp = ei + N_EDGES;

    // ---- CSR build + prep ----
    hipMemsetAsync(hist, 0, 8 * N_NODES * sizeof(int), stream);
    k_deg_prep<<<DD, 256, 0, stream>>>(dstp, hist, rank, x, X, convW, WhiT, WloT, H);
    k_scan1<<<NBLK, 256, 0, stream>>>(hist, off, deg, rowptr, bsum, dinv);
    k_scan2<<<1, 256, 0, stream>>>(bsum, boff, rowptr);
    k_scan3<<<NBLK, 256, 0, stream>>>(rowptr, boff);
    k_fill2<<<FC, 256, 0, stream>>>(srcp, dstp, rowptr, rank, off, deg, batch, eidx, gstart);

    // ---- GCN layers ----
    for (int l = 0; l < NL; ++l) {
        k_gemm<<<1024, 256, 0, stream>>>(X, WhiT + (size_t)l * 16384,
                                         WloT + (size_t)l * 16384, dinv, H);
        k_gather<<<GNB * 4, 256, 0, stream>>>(
            rowptr, eidx, dinv, H, convb + (size_t)l * FEA, X);
    }

    // ---- heads ----
    k_pool<<<NG * 16, 256, 0, stream>>>(X, gstart, nw, nb, out, psum_part);
    k_mlp1<<<128, 256, 0, stream>>>(psum_part, gstart, w1, b1, h1ws);
    k_mlp2<<<128, 256, 0, stream>>>(h1ws, w2, b2, out + N_NODES);
}

// Round 18
// 223.705 us; speedup vs baseline: 1.0364x; 1.0043x over previous
//
#include <hip/hip_runtime.h>

#define N_NODES 50000
#define N_EDGES 800000
#define FEA 128
#define NL 3
#define AH 512
#define NG 64
#define NBLK 196   // ceil(50000/256)

typedef short bf16x8 __attribute__((ext_vector_type(8)));
typedef float f32x4 __attribute__((ext_vector_type(4)));
typedef uint  u32x4 __attribute__((ext_vector_type(4)));

__device__ __forceinline__ ushort f2bf(float f) {   // RTN-even
    uint u = __float_as_uint(f);
    uint r = u + 0x7FFFu + ((u >> 16) & 1u);
    return (ushort)(r >> 16);
}
__device__ __forceinline__ float bf2f(ushort u) {
    return __uint_as_float((uint)u << 16);
}

// Column-sliced layouts: 4 slices of 64B (32 bf16 features) per row.
#define HS ((size_t)(N_NODES + 1) * 32)   // ushorts per H slice
#define XS ((size_t)N_NODES * 32)         // ushorts per X slice

// ---------------- mega: hist+rank (atomic-bound)  ||  gemm layer-0 (compute-bound) ----------------
#define MA 3125            // hist blocks (3125*256 = 800000 edges)
#define MB (MA + 1024)     // gemm0 blocks
#define MC (MB + 1)        // H pad-row zero
__global__ __launch_bounds__(256) void k_mega(const int* __restrict__ dst,
                                              int* __restrict__ deg,
                                              ushort* __restrict__ rank,
                                              const float* __restrict__ x,
                                              const float* __restrict__ convW0,
                                              ushort* __restrict__ H) {
    int blk = blockIdx.x;
    if (blk < MA) {                        // degree histogram + per-edge rank
        int i = blk * 256 + threadIdx.x;
        rank[i] = (ushort)atomicAdd(&deg[dst[i]], 1);
    } else if (blk < MB) {                 // gemm layer 0: A from x f32, B split in-register
        int bid = blk - MA;
        const int wv = threadIdx.x >> 6;
        const int lane = threadIdx.x & 63;
        const int lr = lane & 15;
        const int lk = lane >> 4;

        bf16x8 bhi[2][4], blo[2][4];
#pragma unroll
        for (int ct = 0; ct < 2; ++ct) {
            int col = wv * 32 + ct * 16 + lr;
#pragma unroll
            for (int kf = 0; kf < 4; ++kf) {
#pragma unroll
                for (int j = 0; j < 8; ++j) {
                    float w = convW0[(size_t)(kf * 32 + lk * 8 + j) * FEA + col];
                    ushort h = f2bf(w);
                    bhi[ct][kf][j] = (short)h;
                    blo[ct][kf][j] = (short)f2bf(w - bf2f(h));
                }
            }
        }

        for (int rt = bid; rt < N_NODES / 16; rt += 1024) {
            int r0 = rt * 16;
            const float* xrow = x + (size_t)(r0 + lr) * FEA;
            bf16x8 a[4];
#pragma unroll
            for (int kf = 0; kf < 4; ++kf) {
                float4 u0 = *(const float4*)(xrow + kf * 32 + lk * 8);
                float4 u1 = *(const float4*)(xrow + kf * 32 + lk * 8 + 4);
                a[kf][0] = (short)f2bf(u0.x); a[kf][1] = (short)f2bf(u0.y);
                a[kf][2] = (short)f2bf(u0.z); a[kf][3] = (short)f2bf(u0.w);
                a[kf][4] = (short)f2bf(u1.x); a[kf][5] = (short)f2bf(u1.y);
                a[kf][6] = (short)f2bf(u1.z); a[kf][7] = (short)f2bf(u1.w);
            }
            f32x4 acc0 = {0.f, 0.f, 0.f, 0.f};
            f32x4 acc1 = {0.f, 0.f, 0.f, 0.f};
#pragma unroll
            for (int kf = 0; kf < 4; ++kf) {
                acc0 = __builtin_amdgcn_mfma_f32_16x16x32_bf16(a[kf], bhi[0][kf], acc0, 0, 0, 0);
                acc0 = __builtin_amdgcn_mfma_f32_16x16x32_bf16(a[kf], blo[0][kf], acc0, 0, 0, 0);
                acc1 = __builtin_amdgcn_mfma_f32_16x16x32_bf16(a[kf], bhi[1][kf], acc1, 0, 0, 0);
                acc1 = __builtin_amdgcn_mfma_f32_16x16x32_bf16(a[kf], blo[1][kf], acc1, 0, 0, 0);
            }
            // store UNSCALED (dinv applied later by hscale in k_scan2)
#pragma unroll
            for (int reg = 0; reg < 4; ++reg) {
                int orow = r0 + lk * 4 + reg;
                H[(size_t)wv * HS + (size_t)orow * 32 + lr]      = f2bf(acc0[reg]);
                H[(size_t)wv * HS + (size_t)orow * 32 + 16 + lr] = f2bf(acc1[reg]);
            }
        }
    } else {                               // zero H pad rows (4 slices x 64B)
        if (threadIdx.x < 64) {
            int c = threadIdx.x >> 4, j = threadIdx.x & 15;
            ((uint*)H)[(size_t)c * (HS / 2) + (size_t)N_NODES * 16 + j] = 0;
        }
    }
}

// ---------------- scan helpers ----------------
__device__ __forceinline__ int block_scan_incl(int v, int* wsum) {
    int lane = threadIdx.x & 63, w = threadIdx.x >> 6;
    int s = v;
#pragma unroll
    for (int off = 1; off < 64; off <<= 1) {
        int t = __shfl_up(s, off);
        if (lane >= off) s += t;
    }
    if (lane == 63) wsum[w] = s;
    __syncthreads();
    int woff = 0;
    for (int k = 0; k < w; ++k) woff += wsum[k];
    return woff + s;  // block-wide inclusive
}

__global__ __launch_bounds__(256) void k_scan1(const int* __restrict__ deg,
                                               int* __restrict__ rowptr,
                                               int* __restrict__ bsum,
                                               float* __restrict__ dinv) {
    __shared__ int wsum[4];
    int i = blockIdx.x * 256 + threadIdx.x;
    int v = (i < N_NODES) ? deg[i] : 0;
    int pv = (v + 7) & ~7;                       // pad to multiple of 8
    int incl = block_scan_incl(pv, wsum);
    if (i < N_NODES) {
        rowptr[i] = incl - pv;                   // local exclusive
        dinv[i] = rsqrtf((float)v + 1.0f);
    }
    if (threadIdx.x == 255) bsum[blockIdx.x] = incl;
}

// scan2: block-sum scan (1 block)  ||  hscale: H *= dinv rowwise (3126 blocks)
#define HU4 (4 * (N_NODES + 1) * 4)   // 800016 uint4 elements in H
__global__ __launch_bounds__(256) void k_scan2(int* __restrict__ bsum,
                                               int* __restrict__ boff,
                                               int* __restrict__ rowptr,
                                               const float* __restrict__ dinv,
                                               ushort* __restrict__ H) {
    if (blockIdx.x == 0) {
        __shared__ int wsum[4];
        int v = (threadIdx.x < NBLK) ? bsum[threadIdx.x] : 0;
        int incl = block_scan_incl(v, wsum);
        if (threadIdx.x < NBLK) boff[threadIdx.x] = incl - v;
        if (threadIdx.x == NBLK - 1) rowptr[N_NODES] = incl;  // total padded edges
        return;
    }
    int i = (blockIdx.x - 1) * 256 + threadIdx.x;
    if (i >= HU4) return;
    int c = i / ((N_NODES + 1) * 4);
    int rem = i - c * ((N_NODES + 1) * 4);
    int row = rem >> 2;
    if (row >= N_NODES) return;                  // pad row stays zero
    float dd = dinv[row];
    u32x4 v = ((u32x4*)H)[i];
    uint w;
    w = v.x; v.x = (uint)f2bf(bf2f((ushort)w) * dd) | ((uint)f2bf(bf2f((ushort)(w >> 16)) * dd) << 16);
    w = v.y; v.y = (uint)f2bf(bf2f((ushort)w) * dd) | ((uint)f2bf(bf2f((ushort)(w >> 16)) * dd) << 16);
    w = v.z; v.z = (uint)f2bf(bf2f((ushort)w) * dd) | ((uint)f2bf(bf2f((ushort)(w >> 16)) * dd) << 16);
    w = v.w; v.w = (uint)f2bf(bf2f((ushort)w) * dd) | ((uint)f2bf(bf2f((ushort)(w >> 16)) * dd) << 16);
    ((u32x4*)H)[i] = v;
}

__global__ __launch_bounds__(256) void k_scan3(int* __restrict__ rowptr,
                                               const int* __restrict__ boff) {
    int i = blockIdx.x * 256 + threadIdx.x;
    if (i < N_NODES) rowptr[i] += boff[blockIdx.x];
}

// ---------------- fused: CSR fill | pad slots | graph bounds ----------------
#define FA 3125
#define FB (FA + NBLK)
#define FC (FB + NBLK)
__global__ __launch_bounds__(256) void k_fill2(const int* __restrict__ src,
                                               const int* __restrict__ dst,
                                               const int* __restrict__ rowptr,
                                               const ushort* __restrict__ rank,
                                               const int* __restrict__ deg,
                                               const int* __restrict__ batch,
                                               ushort* __restrict__ eidx,
                                               int* __restrict__ gstart) {
    int blk = blockIdx.x;
    if (blk < FA) {                        // CSR fill (no atomics)
        int e = blk * 256 + threadIdx.x;
        eidx[rowptr[dst[e]] + (int)rank[e]] = (ushort)src[e];
    } else if (blk < FB) {                 // pad slots -> zero row
        int i = (blk - FA) * 256 + threadIdx.x;
        if (i < N_NODES) {
            int d = deg[i], r = rowptr[i];
            int pd = (d + 7) & ~7;
            for (int k = d; k < pd; ++k) eidx[r + k] = (ushort)N_NODES;
        }
    } else {                               // graph bounds from sorted batch
        int i = (blk - FB) * 256 + threadIdx.x;
        if (i < N_NODES) {
            int b = batch[i];
            int bp = (i == 0) ? -1 : batch[i - 1];
            for (int g = bp + 1; g <= b; ++g) gstart[g] = i;
            if (i == N_NODES - 1)
                for (int g = b + 1; g <= NG; ++g) gstart[g] = N_NODES;
        }
    }
}

// ---------------- MFMA GEMM (layers 1,2): H'cs = dinv * (Xcs @ W), W split in-register ----------------
__global__ __launch_bounds__(256) void k_gemm(const ushort* __restrict__ X,
                                              const float* __restrict__ convWl,
                                              const float* __restrict__ dinv,
                                              ushort* __restrict__ H) {
    const int wv = threadIdx.x >> 6;
    const int lane = threadIdx.x & 63;
    const int lr = lane & 15;
    const int lk = lane >> 4;

    bf16x8 bhi[2][4], blo[2][4];
#pragma unroll
    for (int ct = 0; ct < 2; ++ct) {
        int col = wv * 32 + ct * 16 + lr;
#pragma unroll
        for (int kf = 0; kf < 4; ++kf) {
#pragma unroll
            for (int j = 0; j < 8; ++j) {
                float w = convWl[(size_t)(kf * 32 + lk * 8 + j) * FEA + col];
                ushort h = f2bf(w);
                bhi[ct][kf][j] = (short)h;
                blo[ct][kf][j] = (short)f2bf(w - bf2f(h));
            }
        }
    }

    for (int rt = blockIdx.x; rt < N_NODES / 16; rt += gridDim.x) {
        int r0 = rt * 16;
        bf16x8 a[4];
#pragma unroll
        for (int kf = 0; kf < 4; ++kf) {
            a[kf] = *(const bf16x8*)(X + (size_t)kf * XS + (size_t)(r0 + lr) * 32 + lk * 8);
        }
        f32x4 acc0 = {0.f, 0.f, 0.f, 0.f};
        f32x4 acc1 = {0.f, 0.f, 0.f, 0.f};
#pragma unroll
        for (int kf = 0; kf < 4; ++kf) {
            acc0 = __builtin_amdgcn_mfma_f32_16x16x32_bf16(a[kf], bhi[0][kf], acc0, 0, 0, 0);
            acc0 = __builtin_amdgcn_mfma_f32_16x16x32_bf16(a[kf], blo[0][kf], acc0, 0, 0, 0);
            acc1 = __builtin_amdgcn_mfma_f32_16x16x32_bf16(a[kf], bhi[1][kf], acc1, 0, 0, 0);
            acc1 = __builtin_amdgcn_mfma_f32_16x16x32_bf16(a[kf], blo[1][kf], acc1, 0, 0, 0);
        }
#pragma unroll
        for (int reg = 0; reg < 4; ++reg) {
            int orow = r0 + lk * 4 + reg;
            float s = dinv[orow];
            H[(size_t)wv * HS + (size_t)orow * 32 + lr]      = f2bf(acc0[reg] * s);
            H[(size_t)wv * HS + (size_t)orow * 32 + 16 + lr] = f2bf(acc1[reg] * s);
        }
    }
}

// ---------------- gather: 4 lanes/node x one 64B slice; c = blk&3 -> XCD-local ----------------
#define GNPB 64    // nodes per block
#define GNB ((N_NODES + GNPB - 1) / GNPB)
__global__ __launch_bounds__(256) void k_gather(const int* __restrict__ rowptr,
                                                const ushort* __restrict__ eidx,
                                                const float* __restrict__ dinv,
                                                const ushort* __restrict__ H,
                                                const float* __restrict__ b,
                                                ushort* __restrict__ X) {
    int c = blockIdx.x & 3;
    int node = (blockIdx.x >> 2) * GNPB + (threadIdx.x >> 2);
    int l4 = threadIdx.x & 3;              // uint4 offset within 64B slice row
    if (node >= N_NODES) return;
    const uint4* Hs = (const uint4*)H + (size_t)c * (N_NODES + 1) * 4;
    int r0 = rowptr[node], r1 = rowptr[node + 1];

    float a[8] = {0.f, 0.f, 0.f, 0.f, 0.f, 0.f, 0.f, 0.f};
#define ACC8(u)                                                              \
    do {                                                                     \
        a[0] += __uint_as_float((u).x << 16);                                \
        a[1] += __uint_as_float((u).x & 0xffff0000u);                        \
        a[2] += __uint_as_float((u).y << 16);                                \
        a[3] += __uint_as_float((u).y & 0xffff0000u);                        \
        a[4] += __uint_as_float((u).z << 16);                                \
        a[5] += __uint_as_float((u).z & 0xffff0000u);                        \
        a[6] += __uint_as_float((u).w << 16);                                \
        a[7] += __uint_as_float((u).w & 0xffff0000u);                        \
    } while (0)

    uint4 sv = Hs[(size_t)node * 4 + l4];  // self term
    ACC8(sv);

    for (int j = r0; j < r1; j += 8) {     // j 8-aligned -> 16B-aligned
        uint4 ev = *(const uint4*)(eidx + j);   // same addr across node's 4 lanes
        int s0 = ev.x & 0xffff, s1 = ev.x >> 16;
        int s2 = ev.y & 0xffff, s3 = ev.y >> 16;
        int s4 = ev.z & 0xffff, s5 = ev.z >> 16;
        int s6 = ev.w & 0xffff, s7 = ev.w >> 16;
        uint4 h0 = Hs[(size_t)s0 * 4 + l4];
        uint4 h1 = Hs[(size_t)s1 * 4 + l4];
        uint4 h2 = Hs[(size_t)s2 * 4 + l4];
        uint4 h3 = Hs[(size_t)s3 * 4 + l4];
        uint4 h4 = Hs[(size_t)s4 * 4 + l4];
        uint4 h5 = Hs[(size_t)s5 * 4 + l4];
        uint4 h6 = Hs[(size_t)s6 * 4 + l4];
        uint4 h7 = Hs[(size_t)s7 * 4 + l4];
        ACC8(h0); ACC8(h1); ACC8(h2); ACC8(h3);
        ACC8(h4); ACC8(h5); ACC8(h6); ACC8(h7);
    }
#undef ACC8

    float di = dinv[node];
    const float4* b4 = (const float4*)(b + c * 32 + l4 * 8);
    float4 bb0 = b4[0], bb1 = b4[1];
    float o[8];
    o[0] = fmaxf(a[0] * di + bb0.x, 0.f);
    o[1] = fmaxf(a[1] * di + bb0.y, 0.f);
    o[2] = fmaxf(a[2] * di + bb0.z, 0.f);
    o[3] = fmaxf(a[3] * di + bb0.w, 0.f);
    o[4] = fmaxf(a[4] * di + bb1.x, 0.f);
    o[5] = fmaxf(a[5] * di + bb1.y, 0.f);
    o[6] = fmaxf(a[6] * di + bb1.z, 0.f);
    o[7] = fmaxf(a[7] * di + bb1.w, 0.f);

    ushort hs[8];
#pragma unroll
    for (int i = 0; i < 8; ++i) hs[i] = f2bf(o[i]);
    u32x4 hv;
    hv.x = (uint)hs[0] | ((uint)hs[1] << 16);
    hv.y = (uint)hs[2] | ((uint)hs[3] << 16);
    hv.z = (uint)hs[4] | ((uint)hs[5] << 16);
    hv.w = (uint)hs[6] | ((uint)hs[7] << 16);
    __builtin_nontemporal_store(hv, (u32x4*)(X + (size_t)c * XS + (size_t)node * 32 + l4 * 8));
}

// ---------------- pool + node head (no atomics), 16 partials/graph ----------------
__global__ __launch_bounds__(256) void k_pool(const ushort* __restrict__ X,
                                              const int* __restrict__ gstart,
                                              const float* __restrict__ nw,
                                              const float* __restrict__ nbp,
                                              float* __restrict__ out_node,
                                              float* __restrict__ psum_part) {
    int g = blockIdx.x >> 4, p = blockIdx.x & 15;
    int s = gstart[g], e = gstart[g + 1];
    int len = e - s;
    int lp = (len + 15) >> 4;
    int ps = s + p * lp, pe = min(ps + lp, e);
    int q = threadIdx.x >> 6, lane = threadIdx.x & 63;
    const uint* hb = (const uint*)X + (size_t)(lane >> 4) * (XS / 2) + (lane & 15);
    float2 w = ((const float2*)nw)[lane];
    float nbv = nbp[0];
    float2 acc = {0.f, 0.f};
    for (int node = ps + q; node < pe; node += 4) {
        uint hv = hb[(size_t)node * 16];
        float2 v;
        v.x = bf2f((ushort)hv);
        v.y = bf2f((ushort)(hv >> 16));
        acc.x += v.x; acc.y += v.y;
        float dot = v.x * w.x + v.y * w.y;
#pragma unroll
        for (int off = 32; off; off >>= 1) dot += __shfl_down(dot, off);
        if (lane == 0) out_node[node] = dot + nbv;
    }
    __shared__ float lds[4 * FEA];
    lds[q * FEA + lane * 2 + 0] = acc.x;
    lds[q * FEA + lane * 2 + 1] = acc.y;
    __syncthreads();
    if (threadIdx.x < FEA) {
        psum_part[(size_t)blockIdx.x * FEA + threadIdx.x] =
            lds[threadIdx.x] + lds[FEA + threadIdx.x] +
            lds[2 * FEA + threadIdx.x] + lds[3 * FEA + threadIdx.x];
    }
}

// ---------------- MLP layer 1 (direct strided w1 reads) ----------------
__global__ __launch_bounds__(256) void k_mlp1(const float* __restrict__ psum_part,
                                              const int* __restrict__ gstart,
                                              const float* __restrict__ w1,
                                              const float* __restrict__ b1,
                                              float* __restrict__ h1ws) {
    __shared__ float feas[NG * 132];   // pad 132 to spread banks
    for (int idx = threadIdx.x; idx < NG * FEA; idx += 256) {
        int g = idx >> 7, f = idx & 127;
        const float* pp = psum_part + (size_t)g * 16 * FEA + f;
        float sum = 0.f;
#pragma unroll
        for (int p = 0; p < 16; ++p) sum += pp[p * FEA];
        float cnt = fmaxf((float)(gstart[g + 1] - gstart[g]), 1.0f);
        feas[g * 132 + f] = sum / cnt;
    }
    __syncthreads();
    int g = threadIdx.x >> 2, jj = threadIdx.x & 3;
    int j = blockIdx.x * 4 + jj;
    const float* fr = feas + g * 132;
    float a0 = 0.f, a1 = 0.f, a2 = 0.f, a3 = 0.f;
#pragma unroll 8
    for (int k = 0; k < FEA; k += 4) {
        a0 += fr[k + 0] * w1[(k + 0) * AH + j];
        a1 += fr[k + 1] * w1[(k + 1) * AH + j];
        a2 += fr[k + 2] * w1[(k + 2) * AH + j];
        a3 += fr[k + 3] * w1[(k + 3) * AH + j];
    }
    h1ws[(size_t)g * AH + j] = fmaxf((a0 + a1) + (a2 + a3) + b1[j], 0.f);
}

// ---------------- MLP layer 2 (direct strided w2 reads) ----------------
__global__ __launch_bounds__(256) void k_mlp2(const float* __restrict__ h1ws,
                                              const float* __restrict__ w2,
                                              const float* __restrict__ b2,
                                              float* __restrict__ out_fea) {
    int f = blockIdx.x;
    int g = threadIdx.x >> 2, q = threadIdx.x & 3;
    const float* hr = h1ws + (size_t)g * AH + q * 128;
    const float* wr = w2 + (size_t)q * 128 * FEA + f;
    float a0 = 0.f, a1 = 0.f, a2 = 0.f, a3 = 0.f;
#pragma unroll 8
    for (int k = 0; k < 128; k += 4) {
        a0 += hr[k + 0] * wr[(k + 0) * FEA];
        a1 += hr[k + 1] * wr[(k + 1) * FEA];
        a2 += hr[k + 2] * wr[(k + 2) * FEA];
        a3 += hr[k + 3] * wr[(k + 3) * FEA];
    }
    float p = (a0 + a1) + (a2 + a3);
    p += __shfl_xor(p, 1);
    p += __shfl_xor(p, 2);
    if (q == 0) out_fea[(size_t)g * FEA + f] = p + b2[f];
}

extern "C" void kernel_launch(void* const* d_in, const int* in_sizes, int n_in,
                              void* d_out, int out_size, void* d_ws, size_t ws_size,
                              hipStream_t stream) {
    const float* x     = (const float*)d_in[0];
    const int*   ei    = (const int*)d_in[1];
    const int*   batch = (const int*)d_in[2];
    const float* convW = (const float*)d_in[3];
    const float* convb = (const float*)d_in[4];
    const float* w1    = (const float*)d_in[5];
    const float* b1    = (const float*)d_in[6];
    const float* w2    = (const float*)d_in[7];
    const float* b2    = (const float*)d_in[8];
    const float* nw    = (const float*)d_in[9];
    const float* nb    = (const float*)d_in[10];
    float* out = (float*)d_out;

    // workspace layout (4-byte word offsets)
    char* wsb = (char*)d_ws;
    int*    deg    = (int*)wsb;                        // 50000
    float*  dinv   = (float*)(wsb + 50048ll * 4);      // 50000
    int*    rowptr = (int*)(wsb + 100096ll * 4);       // 50001
    int*    bsum   = (int*)(wsb + 150144ll * 4);       // 196
    int*    boff   = (int*)(wsb + 150344ll * 4);       // 196
    int*    gstart = (int*)(wsb + 150544ll * 4);       // 65
    int*    rankw  = (int*)(wsb + 150656ll * 4);       // 400000 words
    ushort* rank   = (ushort*)rankw;                   // 800000 ushort
    float*  h1ws   = (float*)rankw;                    // 32768 w (after fill)
    ushort* eidx   = (ushort*)(wsb + 950656ll * 4);    // <=1.3M ushort
    ushort* H      = (ushort*)(wsb + 1600672ll * 4);   // 4*(N+1)*32 bf16
    ushort* X      = (ushort*)(wsb + 4800736ll * 4);   // 4*N*32 bf16
    float*  psum_part = (float*)(wsb + 8000736ll * 4); // 1024*128 floats

    const int* srcp = ei;
    const int* dstp = ei + N_EDGES;

    // ---- CSR build overlapped with gemm layer 0 ----
    hipMemsetAsync(deg, 0, N_NODES * sizeof(int), stream);
    k_mega<<<MC, 256, 0, stream>>>(dstp, deg, rank, x, convW, H);
    k_scan1<<<NBLK, 256, 0, stream>>>(deg, rowptr, bsum, dinv);
    k_scan2<<<1 + (HU4 + 255) / 256, 256, 0, stream>>>(bsum, boff, rowptr, dinv, H);
    k_scan3<<<NBLK, 256, 0, stream>>>(rowptr, boff);
    k_fill2<<<FC, 256, 0, stream>>>(srcp, dstp, rowptr, rank, deg, batch, eidx, gstart);

    // ---- GCN layers ----
    k_gather<<<GNB * 4, 256, 0, stream>>>(rowptr, eidx, dinv, H, convb, X);
    for (int l = 1; l < NL; ++l) {
        k_gemm<<<1024, 256, 0, stream>>>(X, convW + (size_t)l * FEA * FEA, dinv, H);
        k_gather<<<GNB * 4, 256, 0, stream>>>(
            rowptr, eidx, dinv, H, convb + (size_t)l * FEA, X);
    }

    // ---- heads ----
    k_pool<<<NG * 16, 256, 0, stream>>>(X, gstart, nw, nb, out, psum_part);
    k_mlp1<<<128, 256, 0, stream>>>(psum_part, gstart, w1, b1, h1ws);
    k_mlp2<<<128, 256, 0, stream>>>(h1ws, w2, b2, out + N_NODES);
}